// Round 14
// baseline (292.685 us; speedup 1.0000x reference)
//
#include <hip/hip_runtime.h>
#include <hip/hip_bf16.h>
#include <hip/hip_fp16.h>
#include <math.h>

#define BDIM 256

using v8h = __attribute__((ext_vector_type(8))) _Float16;
using v4f = __attribute__((ext_vector_type(4))) float;

// CSR-build tuning: 512 dst-range buckets, 8192-edge chunks, 4096-edge bucket cap
#define NB  512
#define CH  8192
#define CAP 4096
// pool slices per graph
#define PS  8

// ---------------------------------------------------------------- utilities

__device__ __forceinline__ float wave_max64(float v) {
#pragma unroll
  for (int o = 32; o > 0; o >>= 1) v = fmaxf(v, __shfl_xor(v, o, 64));
  return v;
}
__device__ __forceinline__ float wave_sum64(float v) {
#pragma unroll
  for (int o = 32; o > 0; o >>= 1) v += __shfl_xor(v, o, 64);
  return v;
}

__device__ __forceinline__ float leaky02(float v) {
  return v >= 0.0f ? v : 0.2f * v;
}

// ---- straight-line batched edge accumulates (compile-time NG loads in flight)

// GAT layer 1: 16 lanes/row (256B), 4 edges per load, NG groups.
template <int NG>
__device__ __forceinline__ void acc_edges2(const _Float16* __restrict__ h,
                                           int s_l, float ex0, float ex1,
                                           int grp, int hb, int fb, float* acc) {
  int ss[NG]; float aa[NG]; v8h vv[NG];
#pragma unroll
  for (int u = 0; u < NG; ++u) {
    int idx = u * 4 + grp;               // <= 63; pad lanes carry ex=0, s=0
    ss[u] = __shfl(s_l, idx, 64);
    float a0 = __shfl(ex0, idx, 64);
    float a1 = __shfl(ex1, idx, 64);
    aa[u] = hb ? a1 : a0;
  }
#pragma unroll
  for (int u = 0; u < NG; ++u)
    vv[u] = *(const v8h*)(h + (size_t)ss[u] * 128 + fb);
#pragma unroll
  for (int u = 0; u < NG; ++u)
#pragma unroll
    for (int k = 0; k < 8; ++k) acc[k] += aa[u] * (float)vv[u][k];
}

// GAT layer 2: 8 lanes/row (128B), 8 edges per load, NG groups.
template <int NG>
__device__ __forceinline__ void acc_edges1(const _Float16* __restrict__ h,
                                           int s_l, float ex, int grp, int fb,
                                           float* acc) {
  int ss[NG]; float aa[NG]; v8h vv[NG];
#pragma unroll
  for (int u = 0; u < NG; ++u) {
    int idx = u * 8 + grp;               // <= 63; pads: ex=0, s=0
    ss[u] = __shfl(s_l, idx, 64);
    aa[u] = __shfl(ex, idx, 64);
  }
#pragma unroll
  for (int u = 0; u < NG; ++u)
    vv[u] = *(const v8h*)(h + (size_t)ss[u] * 64 + fb);
#pragma unroll
  for (int u = 0; u < NG; ++u)
#pragma unroll
    for (int k = 0; k < 8; ++k) acc[k] += aa[u] * (float)vv[u][k];
}

// GCN: 8 lanes/row (128B), 8 edges per load, NG groups; validity mask per u.
template <int NG>
__device__ __forceinline__ void acc_edges_g(const _Float16* __restrict__ h,
                                            int s_l, int deg, int grp, int fb,
                                            float* acc) {
  int ss[NG]; float ww[NG]; v8h vv[NG];
#pragma unroll
  for (int u = 0; u < NG; ++u) {
    int idx = u * 8 + grp;
    ss[u] = __shfl(s_l, idx, 64);
    ww[u] = (idx < deg) ? 1.0f : 0.0f;
  }
#pragma unroll
  for (int u = 0; u < NG; ++u)
    vv[u] = *(const v8h*)(h + (size_t)ss[u] * 64 + fb);
#pragma unroll
  for (int u = 0; u < NG; ++u)
#pragma unroll
    for (int k = 0; k < 8; ++k) acc[k] += ww[u] * (float)vv[u][k];
}

// ---------------------------------------------------------------- MFMA GEMM
// C[N,KOUT](fp16) = A[N,KIN] @ W[KIN,KOUT] (fp16 compute, fp32 acc).
// Wave computes 16 rows x KOUT cols. A-frag: A[m=lane&15][k=quad*8+j].
// W transposed to LDS fp16, row padded +8 halves to break bank conflicts.
// C/D frag: col = nt*16 + (lane&15), row = quad*4 + r (HW-verified).
// HEADS>0: fused attention coefficients al_s/al_d from fp32 accumulators.
// SCALE: multiply each output row by rs[row] (GCN dis pre-scaling).
template <int KIN, int KOUT, bool A_FP32, int HEADS, bool SCALE>
__launch_bounds__(BDIM) __global__
void gemm_mfma(const void* __restrict__ Ap, const float* __restrict__ W,
               _Float16* __restrict__ C, const float* __restrict__ rs,
               const float* __restrict__ a_src, const float* __restrict__ a_dst,
               float* __restrict__ al_s, float* __restrict__ al_d, int N) {
  constexpr int KP = KIN + 8;
  constexpr int NT = KOUT / 16;
  __shared__ _Float16 Wt[KOUT * KP];
  int tid = threadIdx.x;
  for (int i = tid; i < KIN * KOUT; i += BDIM) {
    int k = i / KOUT, n = i % KOUT;
    Wt[n * KP + k] = (_Float16)W[i];
  }
  __syncthreads();
  int lane = tid & 63;
  int quad = lane >> 4, l16 = lane & 15;
  int m0 = blockIdx.x * 64 + (tid >> 6) * 16;
  if (m0 >= N) return;  // N % 16 == 0: whole wave in or out
  v4f acc[NT];
#pragma unroll
  for (int nt = 0; nt < NT; ++nt) acc[nt] = (v4f){0.0f, 0.0f, 0.0f, 0.0f};
#pragma unroll
  for (int k0 = 0; k0 < KIN; k0 += 32) {
    v8h a;
    if constexpr (A_FP32) {
      const float* ap = (const float*)Ap + (size_t)(m0 + l16) * KIN + k0 + quad * 8;
#pragma unroll
      for (int j = 0; j < 8; ++j) a[j] = (_Float16)ap[j];
    } else {
      a = *(const v8h*)((const _Float16*)Ap + (size_t)(m0 + l16) * KIN + k0 + quad * 8);
    }
#pragma unroll
    for (int nt = 0; nt < NT; ++nt) {
      v8h b = *(const v8h*)&Wt[(nt * 16 + l16) * KP + k0 + quad * 8];
      acc[nt] = __builtin_amdgcn_mfma_f32_16x16x32_f16(a, b, acc[nt], 0, 0, 0);
    }
  }
  float sc[4];
#pragma unroll
  for (int r = 0; r < 4; ++r) sc[r] = SCALE ? rs[m0 + quad * 4 + r] : 1.0f;
#pragma unroll
  for (int nt = 0; nt < NT; ++nt)
#pragma unroll
    for (int r = 0; r < 4; ++r)
      C[(size_t)(m0 + quad * 4 + r) * KOUT + nt * 16 + l16] =
          (_Float16)(acc[nt][r] * sc[r]);

  if constexpr (HEADS > 0) {
    constexpr int TPH = NT / HEADS;     // MFMA tiles per head
    constexpr int FPH = KOUT / HEADS;   // features per head
    float av_s[NT], av_d[NT];
#pragma unroll
    for (int nt = 0; nt < NT; ++nt) {
      int head = nt / TPH, c = (nt % TPH) * 16 + l16;
      av_s[nt] = a_src[head * FPH + c];
      av_d[nt] = a_dst[head * FPH + c];
    }
#pragma unroll
    for (int r = 0; r < 4; ++r) {
#pragma unroll
      for (int head = 0; head < HEADS; ++head) {
        float ps = 0.0f, pd = 0.0f;
#pragma unroll
        for (int t = 0; t < TPH; ++t) {
          int nt = head * TPH + t;
          ps += acc[nt][r] * av_s[nt];
          pd += acc[nt][r] * av_d[nt];
        }
#pragma unroll
        for (int o = 1; o < 16; o <<= 1) {
          ps += __shfl_xor(ps, o, 64);
          pd += __shfl_xor(pd, o, 64);
        }
        if (l16 == 0) {
          int row = m0 + quad * 4 + r;
          al_s[(size_t)head * N + row] = ps;
          al_d[(size_t)head * N + row] = pd;
        }
      }
    }
  }
}

// ---------------------------------------------------------------- CSR build
// Atomic-free (LDS atomics only): hist -> factored parallel scan -> bucket
// scatter -> per-bucket CSR.

// Pass A: per-chunk LDS histogram over NB dst-range buckets; coalesced count dump.
__launch_bounds__(BDIM) __global__
void hist_a(const int* __restrict__ ei, int E, int TOT, int bw,
            int* __restrict__ counts, int nWG) {
  __shared__ int hist[NB];
  int tid = threadIdx.x, wg = blockIdx.x;
  for (int i = tid; i < NB; i += BDIM) hist[i] = 0;
  __syncthreads();
  int base = wg * CH, lim = min(CH, TOT - base);
  for (int i = tid; i < lim; i += BDIM) {
    int e = base + i;
    int dst = (e < E) ? ei[E + e] : (e - E);
    atomicAdd(&hist[dst / bw], 1);
  }
  __syncthreads();
  for (int b = tid; b < NB; b += BDIM) counts[(size_t)b * nWG + wg] = hist[b];
}

// one wave per bucket: exclusive scan of its nWG chunk-counts (within-bucket)
__launch_bounds__(BDIM) __global__
void scan_bucket(const int* __restrict__ counts, int nWG,
                 int* __restrict__ off, int* __restrict__ btot) {
  int b = blockIdx.x * (BDIM / 64) + (threadIdx.x >> 6);
  int lane = threadIdx.x & 63;
  if (b >= NB) return;
  const int* c = counts + (size_t)b * nWG;
  int* o = off + (size_t)b * nWG;
  int carry = 0;
  for (int base = 0; base < nWG; base += 64) {
    int i = base + lane;
    int v = (i < nWG) ? c[i] : 0;
    int incl = v;
#pragma unroll
    for (int s = 1; s < 64; s <<= 1) {
      int t = __shfl_up(incl, s, 64);
      if (lane >= s) incl += t;
    }
    if (i < nWG) o[i] = carry + incl - v;
    carry += __shfl(incl, 63, 64);
  }
  if (lane == 0) btot[b] = carry;
}

// single 512-thread WG: exclusive scan of the NB bucket totals -> bbase[NB+1]
__launch_bounds__(512) __global__
void scan_tot(const int* __restrict__ btot, int* __restrict__ bbase,
              int* __restrict__ row_ptr, int N, int TOT) {
  __shared__ int wsum[8], wpre[8];
  int tid = threadIdx.x, lane = tid & 63, w = tid >> 6;
  int v = btot[tid];  // NB == 512 == blockDim
  int incl = v;
#pragma unroll
  for (int o = 1; o < 64; o <<= 1) {
    int t = __shfl_up(incl, o, 64);
    if (lane >= o) incl += t;
  }
  if (lane == 63) wsum[w] = incl;
  __syncthreads();
  if (w == 0 && lane < 8) {
    int s = wsum[lane];
#pragma unroll
    for (int o = 1; o < 8; o <<= 1) {
      int t = __shfl_up(s, o, 64);
      if (lane >= o) s += t;
    }
    wpre[lane] = s - wsum[lane];
  }
  __syncthreads();
  bbase[tid] = wpre[w] + incl - v;
  if (tid == 0) { bbase[NB] = TOT; row_ptr[N] = TOT; }
}

// Pass B: scatter edges into bucket-major ebuf, packed (dst_local<<17 | src).
__launch_bounds__(BDIM) __global__
void bucket_b(const int* __restrict__ ei, int E, int TOT, int bw,
              const int* __restrict__ off, const int* __restrict__ bbase,
              int nWG, unsigned int* __restrict__ ebuf) {
  __shared__ int cur[NB];
  int tid = threadIdx.x, wg = blockIdx.x;
  for (int b = tid; b < NB; b += BDIM)
    cur[b] = bbase[b] + off[(size_t)b * nWG + wg];
  __syncthreads();
  int base = wg * CH, lim = min(CH, TOT - base);
  for (int i = tid; i < lim; i += BDIM) {
    int e = base + i;
    int src, dst;
    if (e < E) { src = ei[e]; dst = ei[E + e]; }
    else       { src = dst = e - E; }
    int b = dst / bw;
    int pos = atomicAdd(&cur[b], 1);
    ebuf[pos] = ((unsigned int)(dst - b * bw) << 17) | (unsigned int)src;
  }
}

// Pass C: one WG per bucket. Build CSR segment fully in LDS; all global IO coalesced.
__launch_bounds__(BDIM) __global__
void csr_c(const unsigned int* __restrict__ ebuf, const int* __restrict__ bbase,
           int N, int bw,
           int* __restrict__ row_ptr, float* __restrict__ dis,
           int* __restrict__ csr_src) {
  __shared__ unsigned int eb[CAP];
  __shared__ unsigned int ob[CAP];
  __shared__ int cnt[128], loff[128], cur[128];
  int tid = threadIdx.x, b = blockIdx.x;
  int d0 = b * bw;
  if (d0 >= N) return;
  int width = min(bw, N - d0);
  int sbase = bbase[b];
  int send = bbase[b + 1];
  int nb = send - sbase;
  if (tid < 128) cnt[tid] = 0;
  __syncthreads();
  for (int i = tid; i < nb; i += BDIM) {
    unsigned int v = ebuf[sbase + i];
    eb[i] = v;
    atomicAdd(&cnt[v >> 17], 1);
  }
  __syncthreads();
  if (tid < 64) {  // wave 0: exclusive scan of 128 counters (2 per lane)
    int c0 = cnt[tid * 2], c1 = cnt[tid * 2 + 1];
    int s = c0 + c1;
    int incl = s;
#pragma unroll
    for (int o = 1; o < 64; o <<= 1) {
      int t = __shfl_up(incl, o, 64);
      if (tid >= o) incl += t;
    }
    int excl = incl - s;
    loff[tid * 2] = excl;
    loff[tid * 2 + 1] = excl + c0;
  }
  __syncthreads();
  if (tid < width) {
    row_ptr[d0 + tid] = sbase + loff[tid];
    dis[d0 + tid] = rsqrtf((float)cnt[tid]);  // deg >= 1 (self-loops)
    cur[tid] = loff[tid];
  }
  __syncthreads();
  for (int i = tid; i < nb; i += BDIM) {
    unsigned int v = eb[i];
    int p = atomicAdd(&cur[v >> 17], 1);
    ob[p] = v & 0x1FFFFu;
  }
  __syncthreads();
  for (int i = tid; i < nb; i += BDIM) csr_src[sbase + i] = (int)ob[i];
}

// ---------------------------------------------------------------- GCN gather
// Wide-load: 8 lanes per 128B row -> 8 edges per load; deg-bucketed
// straight-line batch (NG loads in flight). h pre-scaled by dis[src].
__launch_bounds__(BDIM) __global__
void gcn_gather(const __half* __restrict__ h, const int* __restrict__ row_ptr,
                const int* __restrict__ csr_src, const float* __restrict__ dis,
                const float* __restrict__ b, __half* __restrict__ out, int N) {
  int wid = blockIdx.x * (BDIM / 64) + (threadIdx.x >> 6);
  int lane = threadIdx.x & 63;
  if (wid >= N) return;
  int grp = lane >> 3;
  int fb = (lane & 7) * 8;
  int beg = row_ptr[wid], end = row_ptr[wid + 1];
  int deg = end - beg;
  const _Float16* hp = (const _Float16*)h;
  float acc[8];
#pragma unroll
  for (int k = 0; k < 8; ++k) acc[k] = 0.0f;
  if (deg <= 64) {
    int s_l = (lane < deg) ? csr_src[beg + lane] : 0;
    if (deg <= 8)       acc_edges_g<1>(hp, s_l, deg, grp, fb, acc);
    else if (deg <= 16) acc_edges_g<2>(hp, s_l, deg, grp, fb, acc);
    else if (deg <= 32) acc_edges_g<4>(hp, s_l, deg, grp, fb, acc);
    else                acc_edges_g<8>(hp, s_l, deg, grp, fb, acc);
  } else {
    for (int base = beg; base < end; base += 64) {
      int nch = min(64, end - base);
      int s_l = (lane < nch) ? csr_src[base + lane] : 0;
      acc_edges_g<8>(hp, s_l, nch, grp, fb, acc);
    }
  }
#pragma unroll
  for (int o = 8; o < 64; o <<= 1)
#pragma unroll
    for (int k = 0; k < 8; ++k) acc[k] += __shfl_xor(acc[k], o, 64);
  if (lane < 8) {
    float dd = dis[wid];
    v8h ov;
#pragma unroll
    for (int k = 0; k < 8; ++k)
      ov[k] = (_Float16)fmaxf(acc[k] * dd + b[fb + k], 0.0f);
    *(v8h*)((_Float16*)out + (size_t)wid * 64 + fb) = ov;
  }
}

// ---------------------------------------------------------------- GAT (fused)
// Layer 1 (2 heads, 256B rows): 16 lanes/row -> 4 edges per load;
// deg-bucketed straight-line batch (NG loads in flight).
__launch_bounds__(BDIM) __global__
void gat_fused2(const __half* __restrict__ h, const int* __restrict__ row_ptr,
                const int* __restrict__ csr_src, const float* __restrict__ al_s,
                const float* __restrict__ al_d, const float* __restrict__ b,
                __half* __restrict__ out, int N) {
  int wid = blockIdx.x * (BDIM / 64) + (threadIdx.x >> 6);
  int lane = threadIdx.x & 63;
  if (wid >= N) return;
  int grp = lane >> 4;
  int fb = (lane & 15) * 8;
  int hb = (lane & 15) >> 3;
  int beg = row_ptr[wid], end = row_ptr[wid + 1];
  int deg = end - beg;
  float ad0 = al_d[wid], ad1 = al_d[(size_t)N + wid];
  const _Float16* hp = (const _Float16*)h;
  float acc[8];
#pragma unroll
  for (int k = 0; k < 8; ++k) acc[k] = 0.0f;
  float l0, l1;
  if (deg <= 64) {
    int s_l = (lane < deg) ? csr_src[beg + lane] : 0;
    float e0 = (lane < deg) ? leaky02(al_s[s_l] + ad0) : -3.4e38f;
    float e1 = (lane < deg) ? leaky02(al_s[(size_t)N + s_l] + ad1) : -3.4e38f;
    float m0 = wave_max64(e0), m1 = wave_max64(e1);
    float ex0 = (lane < deg) ? expf(e0 - m0) : 0.0f;
    float ex1 = (lane < deg) ? expf(e1 - m1) : 0.0f;
    l0 = wave_sum64(ex0);
    l1 = wave_sum64(ex1);
    if (deg <= 8)       acc_edges2<2>(hp, s_l, ex0, ex1, grp, hb, fb, acc);
    else if (deg <= 16) acc_edges2<4>(hp, s_l, ex0, ex1, grp, hb, fb, acc);
    else if (deg <= 32) acc_edges2<8>(hp, s_l, ex0, ex1, grp, hb, fb, acc);
    else                acc_edges2<16>(hp, s_l, ex0, ex1, grp, hb, fb, acc);
  } else {  // rare: two-pass recompute, chunked
    float m0 = -3.4e38f, m1 = -3.4e38f;
    for (int base = beg; base < end; base += 64) {
      int nch = min(64, end - base);
      int s = (lane < nch) ? csr_src[base + lane] : 0;
      float e0 = (lane < nch) ? leaky02(al_s[s] + ad0) : -3.4e38f;
      float e1 = (lane < nch) ? leaky02(al_s[(size_t)N + s] + ad1) : -3.4e38f;
      m0 = fmaxf(m0, wave_max64(e0));
      m1 = fmaxf(m1, wave_max64(e1));
    }
    l0 = l1 = 0.0f;
    for (int base = beg; base < end; base += 64) {
      int nch = min(64, end - base);
      int s_l = (lane < nch) ? csr_src[base + lane] : 0;
      float ex0 = 0.0f, ex1 = 0.0f;
      if (lane < nch) {
        ex0 = expf(leaky02(al_s[s_l] + ad0) - m0);
        ex1 = expf(leaky02(al_s[(size_t)N + s_l] + ad1) - m1);
      }
      l0 += wave_sum64(ex0);
      l1 += wave_sum64(ex1);
      acc_edges2<16>(hp, s_l, ex0, ex1, grp, hb, fb, acc);
    }
  }
#pragma unroll
  for (int o = 16; o < 64; o <<= 1)
#pragma unroll
    for (int k = 0; k < 8; ++k) acc[k] += __shfl_xor(acc[k], o, 64);
  if (lane < 16) {
    float dn = hb ? l1 : l0;
    v8h ov;
#pragma unroll
    for (int k = 0; k < 8; ++k)
      ov[k] = (_Float16)fmaxf(acc[k] / dn + b[fb + k], 0.0f);  // relu fused
    *(v8h*)((_Float16*)out + (size_t)wid * 128 + fb) = ov;
  }
}

// Layer 2 fused (1 head, 128B rows): 8 lanes/row -> 8 edges per load;
// deg-bucketed straight-line batch; fp16 out, no relu.
__launch_bounds__(BDIM) __global__
void gat_fused1(const __half* __restrict__ h, const int* __restrict__ row_ptr,
                const int* __restrict__ csr_src, const float* __restrict__ al_s,
                const float* __restrict__ al_d, const float* __restrict__ b,
                __half* __restrict__ out, int N) {
  int wid = blockIdx.x * (BDIM / 64) + (threadIdx.x >> 6);
  int lane = threadIdx.x & 63;
  if (wid >= N) return;
  int grp = lane >> 3;
  int fb = (lane & 7) * 8;
  int beg = row_ptr[wid], end = row_ptr[wid + 1];
  int deg = end - beg;
  float ad = al_d[wid];
  const _Float16* hp = (const _Float16*)h;
  float acc[8];
#pragma unroll
  for (int k = 0; k < 8; ++k) acc[k] = 0.0f;
  float l;
  if (deg <= 64) {
    int s_l = (lane < deg) ? csr_src[beg + lane] : 0;
    float e = (lane < deg) ? leaky02(al_s[s_l] + ad) : -3.4e38f;
    float m = wave_max64(e);
    float ex = (lane < deg) ? expf(e - m) : 0.0f;
    l = wave_sum64(ex);
    if (deg <= 8)       acc_edges1<1>(hp, s_l, ex, grp, fb, acc);
    else if (deg <= 16) acc_edges1<2>(hp, s_l, ex, grp, fb, acc);
    else if (deg <= 32) acc_edges1<4>(hp, s_l, ex, grp, fb, acc);
    else                acc_edges1<8>(hp, s_l, ex, grp, fb, acc);
  } else {
    float m = -3.4e38f;
    for (int base = beg; base < end; base += 64) {
      int nch = min(64, end - base);
      int s = (lane < nch) ? csr_src[base + lane] : 0;
      float e = (lane < nch) ? leaky02(al_s[s] + ad) : -3.4e38f;
      m = fmaxf(m, wave_max64(e));
    }
    l = 0.0f;
    for (int base = beg; base < end; base += 64) {
      int nch = min(64, end - base);
      int s_l = (lane < nch) ? csr_src[base + lane] : 0;
      float ex = (lane < nch) ? expf(leaky02(al_s[s_l] + ad) - m) : 0.0f;
      l += wave_sum64(ex);
      acc_edges1<8>(hp, s_l, ex, grp, fb, acc);
    }
  }
#pragma unroll
  for (int o = 8; o < 64; o <<= 1)
#pragma unroll
    for (int k = 0; k < 8; ++k) acc[k] += __shfl_xor(acc[k], o, 64);
  if (lane < 8) {
    v8h ov;
#pragma unroll
    for (int k = 0; k < 8; ++k)
      ov[k] = (_Float16)(acc[k] / l + b[fb + k]);  // no relu on layer 2
    *(v8h*)((_Float16*)out + (size_t)wid * 64 + fb) = ov;
  }
}

// ---------------------------------------------------------------- pool + head
__device__ __forceinline__ int lower_bound(const int* __restrict__ a, int n, int v) {
  int lo = 0, hi = n;
  while (lo < hi) {
    int mid = (lo + hi) >> 1;
    if (a[mid] < v) lo = mid + 1; else hi = mid;
  }
  return lo;
}

// stage A: wave per (graph, slice): sum a contiguous slice of the graph's rows.
__launch_bounds__(BDIM) __global__
void pool_partial(const __half* __restrict__ x3, const int* __restrict__ batch,
                  float* __restrict__ part, int N, int G) {
  int wid = blockIdx.x * (BDIM / 64) + (threadIdx.x >> 6);
  int lane = threadIdx.x & 63;
  if (wid >= G * PS) return;
  int g = wid / PS, s = wid % PS;
  int beg = lower_bound(batch, N, g);
  int end = lower_bound(batch, N, g + 1);
  int len = end - beg;
  int lo = beg + (int)((long long)len * s / PS);
  int hi = beg + (int)((long long)len * (s + 1) / PS);
  float acc = 0.0f;
  int n = lo;
  for (; n + 4 <= hi; n += 4) {  // 4 independent line-loads in flight
    float a0 = __half2float(x3[(size_t)(n + 0) * 64 + lane]);
    float a1 = __half2float(x3[(size_t)(n + 1) * 64 + lane]);
    float a2 = __half2float(x3[(size_t)(n + 2) * 64 + lane]);
    float a3 = __half2float(x3[(size_t)(n + 3) * 64 + lane]);
    acc += (a0 + a1) + (a2 + a3);
  }
  for (; n < hi; ++n) acc += __half2float(x3[(size_t)n * 64 + lane]);
  part[(size_t)wid * 64 + lane] = acc;
}

// stage B: wave per graph: reduce PS partials, mean, FC, log_softmax.
__launch_bounds__(BDIM) __global__
void pool_head(const float* __restrict__ part, const int* __restrict__ batch,
               const float* __restrict__ Wfc, const float* __restrict__ bfc,
               float* __restrict__ out, int N, int G) {
  int wid = blockIdx.x * (BDIM / 64) + (threadIdx.x >> 6);
  int lane = threadIdx.x & 63;
  if (wid >= G) return;
  float acc = 0.0f;
#pragma unroll
  for (int s = 0; s < PS; ++s) acc += part[((size_t)wid * PS + s) * 64 + lane];
  int beg = lower_bound(batch, N, wid);
  int end = lower_bound(batch, N, wid + 1);
  float p = (end > beg) ? acc / (float)(end - beg) : 0.0f;
  float l0 = wave_sum64(p * Wfc[lane * 2 + 0]);
  float l1 = wave_sum64(p * Wfc[lane * 2 + 1]);
  if (lane == 0) {
    l0 += bfc[0];
    l1 += bfc[1];
    float m = fmaxf(l0, l1);
    float ls = m + logf(expf(l0 - m) + expf(l1 - m));
    out[wid * 2 + 0] = l0 - ls;
    out[wid * 2 + 1] = l1 - ls;
  }
}

// ---------------------------------------------------------------- launch

static inline int cdiv(int a, int b) { return (a + b - 1) / b; }

extern "C" void kernel_launch(void* const* d_in, const int* in_sizes, int n_in,
                              void* d_out, int out_size, void* d_ws, size_t ws_size,
                              hipStream_t stream) {
  const float* x      = (const float*)d_in[0];
  const int*   ei     = (const int*)d_in[1];
  const int*   batch  = (const int*)d_in[2];
  const float* W1     = (const float*)d_in[3];
  const float* b1     = (const float*)d_in[4];
  const float* W2     = (const float*)d_in[5];
  const float* a_src2 = (const float*)d_in[6];
  const float* a_dst2 = (const float*)d_in[7];
  const float* b2     = (const float*)d_in[8];
  const float* W3     = (const float*)d_in[9];
  const float* a_src3 = (const float*)d_in[10];
  const float* a_dst3 = (const float*)d_in[11];
  const float* b3     = (const float*)d_in[12];
  const float* Wfc    = (const float*)d_in[13];
  const float* bfc    = (const float*)d_in[14];
  float* out = (float*)d_out;

  const int N = in_sizes[2];       // 50000
  const int E = in_sizes[1] / 2;   // 800000
  const int G = out_size / 2;      // 512
  const int TOT = E + N;           // edges incl. self-loops
  const int bw  = cdiv(N, NB);     // dst-range per bucket (98)
  const int nWG = cdiv(TOT, CH);   // chunks (104)
  const int M   = NB * nWG;        // count-matrix size

  // workspace layout, fp16 buffers first (16B-aligned offsets)
  char* wsb = (char*)d_ws;
  __half* h1    = (__half*)wsb;                       // N*64 fp16
  __half* h2    = h1 + (size_t)N * 64;                // N*128 fp16 (reused as h3)
  __half* out1h = h2 + (size_t)N * 128;               // N*64 fp16 (x1)
  __half* out2h = out1h + (size_t)N * 64;             // N*128 fp16 (x2)
  __half* out3h = out2h + (size_t)N * 128;            // N*64 fp16 (x3)
  float*  dis   = (float*)(out3h + (size_t)N * 64);   // N
  float*  al_s  = dis + N;                            // N*2 planar
  float*  al_d  = al_s + (size_t)N * 2;               // N*2 planar
  float*  part  = al_d + (size_t)N * 2;               // G*PS*64
  int* counts   = (int*)(part + (size_t)G * PS * 64); // M
  int* off      = counts + M;                         // M
  int* btot     = off + M;                            // NB
  int* bbase    = btot + NB;                          // NB+1
  unsigned int* ebuf = (unsigned int*)(bbase + NB + 1);  // TOT
  int* csr_src  = (int*)(ebuf + TOT);                 // TOT
  int* row_ptr  = csr_src + TOT;                      // N+1

  // ---- CSR build: atomic-free radix bucketing, factored parallel scan
  hist_a<<<nWG, BDIM, 0, stream>>>(ei, E, TOT, bw, counts, nWG);
  scan_bucket<<<cdiv(NB, 4), BDIM, 0, stream>>>(counts, nWG, off, btot);
  scan_tot<<<1, 512, 0, stream>>>(btot, bbase, row_ptr, N, TOT);
  bucket_b<<<nWG, BDIM, 0, stream>>>(ei, E, TOT, bw, off, bbase, nWG, ebuf);
  csr_c<<<NB, BDIM, 0, stream>>>(ebuf, bbase, N, bw, row_ptr, dis, csr_src);

  // ---- GCN layer (h1 pre-scaled by dis[row] in GEMM epilogue)
  gemm_mfma<128, 64, true, 0, true><<<cdiv(N, 64), BDIM, 0, stream>>>(
      x, W1, (_Float16*)h1, dis, nullptr, nullptr, nullptr, nullptr, N);
  gcn_gather<<<cdiv(N, 4), BDIM, 0, stream>>>(h1, row_ptr, csr_src, dis, b1, out1h, N);

  // ---- GAT layer 1 (heads=2, concat; att_coef fused into GEMM epilogue,
  //      softmax fused into accumulate)
  gemm_mfma<64, 128, false, 2, false><<<cdiv(N, 64), BDIM, 0, stream>>>(
      out1h, W2, (_Float16*)h2, nullptr, a_src2, a_dst2, al_s, al_d, N);
  gat_fused2<<<cdiv(N, 4), BDIM, 0, stream>>>(h2, row_ptr, csr_src, al_s, al_d,
                                              b2, out2h, N);

  // ---- GAT layer 2 (heads=1, mean == identity)
  __half* h3 = h2;  // h2 dead after gat_fused2
  gemm_mfma<128, 64, false, 1, false><<<cdiv(N, 64), BDIM, 0, stream>>>(
      out2h, W3, (_Float16*)h3, nullptr, a_src3, a_dst3, al_s, al_d, N);
  gat_fused1<<<cdiv(N, 4), BDIM, 0, stream>>>(h3, row_ptr, csr_src, al_s, al_d,
                                              b3, out3h, N);

  // ---- global mean pool + fc + log_softmax (atomic-free; batch is sorted)
  pool_partial<<<cdiv(G * PS, 4), BDIM, 0, stream>>>(out3h, batch, part, N, G);
  pool_head<<<cdiv(G, 4), BDIM, 0, stream>>>(part, batch, Wfc, bfc, out, N, G);
}

// Round 15
// 275.363 us; speedup vs baseline: 1.0629x; 1.0629x over previous
//
#include <hip/hip_runtime.h>
#include <hip/hip_bf16.h>
#include <hip/hip_fp16.h>
#include <math.h>

#define BDIM 256

using v8h = __attribute__((ext_vector_type(8))) _Float16;
using v4f = __attribute__((ext_vector_type(4))) float;

// CSR-build tuning: 512 dst-range buckets, 8192-edge chunks, 4096-edge bucket cap
#define NB  512
#define CH  8192
#define CAP 4096
// pool slices per graph
#define PS  8

// ---------------------------------------------------------------- utilities

__device__ __forceinline__ float wave_max64(float v) {
#pragma unroll
  for (int o = 32; o > 0; o >>= 1) v = fmaxf(v, __shfl_xor(v, o, 64));
  return v;
}
__device__ __forceinline__ float wave_sum64(float v) {
#pragma unroll
  for (int o = 32; o > 0; o >>= 1) v += __shfl_xor(v, o, 64);
  return v;
}

__device__ __forceinline__ float leaky02(float v) {
  return v >= 0.0f ? v : 0.2f * v;
}

__device__ __forceinline__ v8h bcast8(_Float16 a) {
  v8h r = {a, a, a, a, a, a, a, a};
  return r;
}

// ---------------------------------------------------------------- MFMA GEMM
// C[N,KOUT](fp16) = A[N,KIN] @ W[KIN,KOUT] (fp16 compute, fp32 acc).
// Wave computes 16 rows x KOUT cols. A-frag: A[m=lane&15][k=quad*8+j].
// W transposed to LDS fp16, row padded +8 halves to break bank conflicts.
// C/D frag: col = nt*16 + (lane&15), row = quad*4 + r (HW-verified).
// HEADS>0: fused attention coefficients al_s/al_d from fp32 accumulators.
// SCALE: multiply each output row by rs[row] (GCN dis pre-scaling).
template <int KIN, int KOUT, bool A_FP32, int HEADS, bool SCALE>
__launch_bounds__(BDIM) __global__
void gemm_mfma(const void* __restrict__ Ap, const float* __restrict__ W,
               _Float16* __restrict__ C, const float* __restrict__ rs,
               const float* __restrict__ a_src, const float* __restrict__ a_dst,
               float* __restrict__ al_s, float* __restrict__ al_d, int N) {
  constexpr int KP = KIN + 8;
  constexpr int NT = KOUT / 16;
  __shared__ _Float16 Wt[KOUT * KP];
  int tid = threadIdx.x;
  for (int i = tid; i < KIN * KOUT; i += BDIM) {
    int k = i / KOUT, n = i % KOUT;
    Wt[n * KP + k] = (_Float16)W[i];
  }
  __syncthreads();
  int lane = tid & 63;
  int quad = lane >> 4, l16 = lane & 15;
  int m0 = blockIdx.x * 64 + (tid >> 6) * 16;
  if (m0 >= N) return;  // N % 16 == 0: whole wave in or out
  v4f acc[NT];
#pragma unroll
  for (int nt = 0; nt < NT; ++nt) acc[nt] = (v4f){0.0f, 0.0f, 0.0f, 0.0f};
#pragma unroll
  for (int k0 = 0; k0 < KIN; k0 += 32) {
    v8h a;
    if constexpr (A_FP32) {
      const float* ap = (const float*)Ap + (size_t)(m0 + l16) * KIN + k0 + quad * 8;
#pragma unroll
      for (int j = 0; j < 8; ++j) a[j] = (_Float16)ap[j];
    } else {
      a = *(const v8h*)((const _Float16*)Ap + (size_t)(m0 + l16) * KIN + k0 + quad * 8);
    }
#pragma unroll
    for (int nt = 0; nt < NT; ++nt) {
      v8h b = *(const v8h*)&Wt[(nt * 16 + l16) * KP + k0 + quad * 8];
      acc[nt] = __builtin_amdgcn_mfma_f32_16x16x32_f16(a, b, acc[nt], 0, 0, 0);
    }
  }
  float sc[4];
#pragma unroll
  for (int r = 0; r < 4; ++r) sc[r] = SCALE ? rs[m0 + quad * 4 + r] : 1.0f;
#pragma unroll
  for (int nt = 0; nt < NT; ++nt)
#pragma unroll
    for (int r = 0; r < 4; ++r)
      C[(size_t)(m0 + quad * 4 + r) * KOUT + nt * 16 + l16] =
          (_Float16)(acc[nt][r] * sc[r]);

  if constexpr (HEADS > 0) {
    constexpr int TPH = NT / HEADS;     // MFMA tiles per head
    constexpr int FPH = KOUT / HEADS;   // features per head
    float av_s[NT], av_d[NT];
#pragma unroll
    for (int nt = 0; nt < NT; ++nt) {
      int head = nt / TPH, c = (nt % TPH) * 16 + l16;
      av_s[nt] = a_src[head * FPH + c];
      av_d[nt] = a_dst[head * FPH + c];
    }
#pragma unroll
    for (int r = 0; r < 4; ++r) {
#pragma unroll
      for (int head = 0; head < HEADS; ++head) {
        float ps = 0.0f, pd = 0.0f;
#pragma unroll
        for (int t = 0; t < TPH; ++t) {
          int nt = head * TPH + t;
          ps += acc[nt][r] * av_s[nt];
          pd += acc[nt][r] * av_d[nt];
        }
#pragma unroll
        for (int o = 1; o < 16; o <<= 1) {
          ps += __shfl_xor(ps, o, 64);
          pd += __shfl_xor(pd, o, 64);
        }
        if (l16 == 0) {
          int row = m0 + quad * 4 + r;
          al_s[(size_t)head * N + row] = ps;
          al_d[(size_t)head * N + row] = pd;
        }
      }
    }
  }
}

// ---------------------------------------------------------------- CSR build
// Atomic-free (LDS atomics only): hist -> factored parallel scan -> bucket
// scatter -> per-bucket CSR.

// Pass A: per-chunk LDS histogram over NB dst-range buckets; coalesced count dump.
__launch_bounds__(BDIM) __global__
void hist_a(const int* __restrict__ ei, int E, int TOT, int bw,
            int* __restrict__ counts, int nWG) {
  __shared__ int hist[NB];
  int tid = threadIdx.x, wg = blockIdx.x;
  for (int i = tid; i < NB; i += BDIM) hist[i] = 0;
  __syncthreads();
  int base = wg * CH, lim = min(CH, TOT - base);
  for (int i = tid; i < lim; i += BDIM) {
    int e = base + i;
    int dst = (e < E) ? ei[E + e] : (e - E);
    atomicAdd(&hist[dst / bw], 1);
  }
  __syncthreads();
  for (int b = tid; b < NB; b += BDIM) counts[(size_t)b * nWG + wg] = hist[b];
}

// one wave per bucket: exclusive scan of its nWG chunk-counts (within-bucket)
__launch_bounds__(BDIM) __global__
void scan_bucket(const int* __restrict__ counts, int nWG,
                 int* __restrict__ off, int* __restrict__ btot) {
  int b = blockIdx.x * (BDIM / 64) + (threadIdx.x >> 6);
  int lane = threadIdx.x & 63;
  if (b >= NB) return;
  const int* c = counts + (size_t)b * nWG;
  int* o = off + (size_t)b * nWG;
  int carry = 0;
  for (int base = 0; base < nWG; base += 64) {
    int i = base + lane;
    int v = (i < nWG) ? c[i] : 0;
    int incl = v;
#pragma unroll
    for (int s = 1; s < 64; s <<= 1) {
      int t = __shfl_up(incl, s, 64);
      if (lane >= s) incl += t;
    }
    if (i < nWG) o[i] = carry + incl - v;
    carry += __shfl(incl, 63, 64);
  }
  if (lane == 0) btot[b] = carry;
}

// single 512-thread WG: exclusive scan of the NB bucket totals -> bbase[NB+1]
__launch_bounds__(512) __global__
void scan_tot(const int* __restrict__ btot, int* __restrict__ bbase,
              int* __restrict__ row_ptr, int N, int TOT) {
  __shared__ int wsum[8], wpre[8];
  int tid = threadIdx.x, lane = tid & 63, w = tid >> 6;
  int v = btot[tid];  // NB == 512 == blockDim
  int incl = v;
#pragma unroll
  for (int o = 1; o < 64; o <<= 1) {
    int t = __shfl_up(incl, o, 64);
    if (lane >= o) incl += t;
  }
  if (lane == 63) wsum[w] = incl;
  __syncthreads();
  if (w == 0 && lane < 8) {
    int s = wsum[lane];
#pragma unroll
    for (int o = 1; o < 8; o <<= 1) {
      int t = __shfl_up(s, o, 64);
      if (lane >= o) s += t;
    }
    wpre[lane] = s - wsum[lane];
  }
  __syncthreads();
  bbase[tid] = wpre[w] + incl - v;
  if (tid == 0) { bbase[NB] = TOT; row_ptr[N] = TOT; }
}

// Pass B: scatter edges into bucket-major ebuf, packed (dst_local<<17 | src).
__launch_bounds__(BDIM) __global__
void bucket_b(const int* __restrict__ ei, int E, int TOT, int bw,
              const int* __restrict__ off, const int* __restrict__ bbase,
              int nWG, unsigned int* __restrict__ ebuf) {
  __shared__ int cur[NB];
  int tid = threadIdx.x, wg = blockIdx.x;
  for (int b = tid; b < NB; b += BDIM)
    cur[b] = bbase[b] + off[(size_t)b * nWG + wg];
  __syncthreads();
  int base = wg * CH, lim = min(CH, TOT - base);
  for (int i = tid; i < lim; i += BDIM) {
    int e = base + i;
    int src, dst;
    if (e < E) { src = ei[e]; dst = ei[E + e]; }
    else       { src = dst = e - E; }
    int b = dst / bw;
    int pos = atomicAdd(&cur[b], 1);
    ebuf[pos] = ((unsigned int)(dst - b * bw) << 17) | (unsigned int)src;
  }
}

// Pass C: one WG per bucket. Build CSR segment fully in LDS; all global IO coalesced.
__launch_bounds__(BDIM) __global__
void csr_c(const unsigned int* __restrict__ ebuf, const int* __restrict__ bbase,
           int N, int bw,
           int* __restrict__ row_ptr, float* __restrict__ dis,
           int* __restrict__ csr_src) {
  __shared__ unsigned int eb[CAP];
  __shared__ unsigned int ob[CAP];
  __shared__ int cnt[128], loff[128], cur[128];
  int tid = threadIdx.x, b = blockIdx.x;
  int d0 = b * bw;
  if (d0 >= N) return;
  int width = min(bw, N - d0);
  int sbase = bbase[b];
  int send = bbase[b + 1];
  int nb = send - sbase;
  if (tid < 128) cnt[tid] = 0;
  __syncthreads();
  for (int i = tid; i < nb; i += BDIM) {
    unsigned int v = ebuf[sbase + i];
    eb[i] = v;
    atomicAdd(&cnt[v >> 17], 1);
  }
  __syncthreads();
  if (tid < 64) {  // wave 0: exclusive scan of 128 counters (2 per lane)
    int c0 = cnt[tid * 2], c1 = cnt[tid * 2 + 1];
    int s = c0 + c1;
    int incl = s;
#pragma unroll
    for (int o = 1; o < 64; o <<= 1) {
      int t = __shfl_up(incl, o, 64);
      if (tid >= o) incl += t;
    }
    int excl = incl - s;
    loff[tid * 2] = excl;
    loff[tid * 2 + 1] = excl + c0;
  }
  __syncthreads();
  if (tid < width) {
    row_ptr[d0 + tid] = sbase + loff[tid];
    dis[d0 + tid] = rsqrtf((float)cnt[tid]);  // deg >= 1 (self-loops)
    cur[tid] = loff[tid];
  }
  __syncthreads();
  for (int i = tid; i < nb; i += BDIM) {
    unsigned int v = eb[i];
    int p = atomicAdd(&cur[v >> 17], 1);
    ob[p] = v & 0x1FFFFu;
  }
  __syncthreads();
  for (int i = tid; i < nb; i += BDIM) csr_src[sbase + i] = (int)ob[i];
}

// ---------------------------------------------------------------- GCN gather
// Wide-load: 8 lanes per 128B row -> 8 edges per global_load_dwordx4 (1KB/inst),
// guarded batch of up to 8 loads; packed-fp16 accumulate (v_pk_fma_f16).
// h pre-scaled by dis[src].
__launch_bounds__(BDIM) __global__
void gcn_gather(const __half* __restrict__ h, const int* __restrict__ row_ptr,
                const int* __restrict__ csr_src, const float* __restrict__ dis,
                const float* __restrict__ b, __half* __restrict__ out, int N) {
  int wid = blockIdx.x * (BDIM / 64) + (threadIdx.x >> 6);
  int lane = threadIdx.x & 63;
  if (wid >= N) return;
  int grp = lane >> 3;
  int fb = (lane & 7) * 8;
  int beg = row_ptr[wid], end = row_ptr[wid + 1];
  const _Float16* hp = (const _Float16*)h;
  v8h acch;
#pragma unroll
  for (int k = 0; k < 8; ++k) acch[k] = (_Float16)0;
  for (int base = beg; base < end; base += 64) {
    int nch = min(64, end - base);
    int s_l = (lane < nch) ? csr_src[base + lane] : 0;
    int ng = (nch + 7) >> 3;  // wave-uniform, <= 8
    int ss[8]; _Float16 ww[8]; v8h vv[8];
#pragma unroll
    for (int u = 0; u < 8; ++u)
      if (u < ng) {
        int idx = u * 8 + grp;
        ss[u] = __shfl(s_l, idx, 64);
        ww[u] = (idx < nch) ? (_Float16)1 : (_Float16)0;
      }
#pragma unroll
    for (int u = 0; u < 8; ++u)
      if (u < ng) vv[u] = *(const v8h*)(hp + (size_t)ss[u] * 64 + fb);
#pragma unroll
    for (int u = 0; u < 8; ++u)
      if (u < ng) acch += bcast8(ww[u]) * vv[u];
  }
  float acc[8];
#pragma unroll
  for (int k = 0; k < 8; ++k) acc[k] = (float)acch[k];
#pragma unroll
  for (int o = 8; o < 64; o <<= 1)
#pragma unroll
    for (int k = 0; k < 8; ++k) acc[k] += __shfl_xor(acc[k], o, 64);
  if (lane < 8) {
    float dd = dis[wid];
    v8h ov;
#pragma unroll
    for (int k = 0; k < 8; ++k)
      ov[k] = (_Float16)fmaxf(acc[k] * dd + b[fb + k], 0.0f);
    *(v8h*)((_Float16*)out + (size_t)wid * 64 + fb) = ov;
  }
}

// ---------------------------------------------------------------- GAT (fused)
// Layer 1 (2 heads, 256B rows): 16 lanes/row -> 4 edges per load; 4 loads
// batched per 16-edge block + step-4 remainder; packed-fp16 accumulate.
__launch_bounds__(BDIM) __global__
void gat_fused2(const __half* __restrict__ h, const int* __restrict__ row_ptr,
                const int* __restrict__ csr_src, const float* __restrict__ al_s,
                const float* __restrict__ al_d, const float* __restrict__ b,
                __half* __restrict__ out, int N) {
  int wid = blockIdx.x * (BDIM / 64) + (threadIdx.x >> 6);
  int lane = threadIdx.x & 63;
  if (wid >= N) return;
  int grp = lane >> 4;
  int fb = (lane & 15) * 8;
  int hb = (lane & 15) >> 3;
  int beg = row_ptr[wid], end = row_ptr[wid + 1];
  int deg = end - beg;
  float ad0 = al_d[wid], ad1 = al_d[(size_t)N + wid];
  const _Float16* hp = (const _Float16*)h;
  v8h acch;
#pragma unroll
  for (int k = 0; k < 8; ++k) acch[k] = (_Float16)0;
  float l0, l1;
  if (deg <= 64) {
    int s_l = (lane < deg) ? csr_src[beg + lane] : 0;
    float e0 = (lane < deg) ? leaky02(al_s[s_l] + ad0) : -3.4e38f;
    float e1 = (lane < deg) ? leaky02(al_s[(size_t)N + s_l] + ad1) : -3.4e38f;
    float m0 = wave_max64(e0), m1 = wave_max64(e1);
    float ex0 = (lane < deg) ? expf(e0 - m0) : 0.0f;
    float ex1 = (lane < deg) ? expf(e1 - m1) : 0.0f;
    l0 = wave_sum64(ex0);
    l1 = wave_sum64(ex1);
    int jfull = deg & ~15;
    for (int j = 0; j < jfull; j += 16) {  // 4 loads in flight
      int ss[4]; _Float16 aa[4]; v8h vv[4];
#pragma unroll
      for (int u = 0; u < 4; ++u) {
        int idx = j + u * 4 + grp;  // <= 63
        ss[u] = __shfl(s_l, idx, 64);
        float a0 = __shfl(ex0, idx, 64);
        float a1 = __shfl(ex1, idx, 64);
        aa[u] = (_Float16)(hb ? a1 : a0);
      }
#pragma unroll
      for (int u = 0; u < 4; ++u)
        vv[u] = *(const v8h*)(hp + (size_t)ss[u] * 128 + fb);
#pragma unroll
      for (int u = 0; u < 4; ++u) acch += bcast8(aa[u]) * vv[u];
    }
    for (int j = jfull; j < deg; j += 4) {
      int idx = j + grp;  // pads carry ex=0, s=0
      int s = __shfl(s_l, idx, 64);
      float a0 = __shfl(ex0, idx, 64);
      float a1 = __shfl(ex1, idx, 64);
      _Float16 a = (_Float16)(hb ? a1 : a0);
      v8h v = *(const v8h*)(hp + (size_t)s * 128 + fb);
      acch += bcast8(a) * v;
    }
  } else {  // rare: two-pass recompute, chunked
    float m0 = -3.4e38f, m1 = -3.4e38f;
    for (int base = beg; base < end; base += 64) {
      int nch = min(64, end - base);
      int s = (lane < nch) ? csr_src[base + lane] : 0;
      float e0 = (lane < nch) ? leaky02(al_s[s] + ad0) : -3.4e38f;
      float e1 = (lane < nch) ? leaky02(al_s[(size_t)N + s] + ad1) : -3.4e38f;
      m0 = fmaxf(m0, wave_max64(e0));
      m1 = fmaxf(m1, wave_max64(e1));
    }
    l0 = l1 = 0.0f;
    for (int base = beg; base < end; base += 64) {
      int nch = min(64, end - base);
      int s_l = (lane < nch) ? csr_src[base + lane] : 0;
      float ex0 = 0.0f, ex1 = 0.0f;
      if (lane < nch) {
        ex0 = expf(leaky02(al_s[s_l] + ad0) - m0);
        ex1 = expf(leaky02(al_s[(size_t)N + s_l] + ad1) - m1);
      }
      l0 += wave_sum64(ex0);
      l1 += wave_sum64(ex1);
      for (int j = 0; j < nch; j += 4) {
        int idx = j + grp;
        int s = __shfl(s_l, idx, 64);
        float a0 = __shfl(ex0, idx, 64);
        float a1 = __shfl(ex1, idx, 64);
        _Float16 a = (_Float16)(hb ? a1 : a0);
        v8h v = *(const v8h*)(hp + (size_t)s * 128 + fb);
        acch += bcast8(a) * v;
      }
    }
  }
  float acc[8];
#pragma unroll
  for (int k = 0; k < 8; ++k) acc[k] = (float)acch[k];
#pragma unroll
  for (int o = 16; o < 64; o <<= 1)
#pragma unroll
    for (int k = 0; k < 8; ++k) acc[k] += __shfl_xor(acc[k], o, 64);
  if (lane < 16) {
    float dn = hb ? l1 : l0;
    v8h ov;
#pragma unroll
    for (int k = 0; k < 8; ++k)
      ov[k] = (_Float16)fmaxf(acc[k] / dn + b[fb + k], 0.0f);  // relu fused
    *(v8h*)((_Float16*)out + (size_t)wid * 128 + fb) = ov;
  }
}

// Layer 2 fused (1 head, 128B rows): 8 lanes/row -> 8 edges per load, up to 8
// guarded loads batched; packed-fp16 accumulate; fp16 out, no relu.
__launch_bounds__(BDIM) __global__
void gat_fused1(const __half* __restrict__ h, const int* __restrict__ row_ptr,
                const int* __restrict__ csr_src, const float* __restrict__ al_s,
                const float* __restrict__ al_d, const float* __restrict__ b,
                __half* __restrict__ out, int N) {
  int wid = blockIdx.x * (BDIM / 64) + (threadIdx.x >> 6);
  int lane = threadIdx.x & 63;
  if (wid >= N) return;
  int grp = lane >> 3;
  int fb = (lane & 7) * 8;
  int beg = row_ptr[wid], end = row_ptr[wid + 1];
  int deg = end - beg;
  float ad = al_d[wid];
  const _Float16* hp = (const _Float16*)h;
  v8h acch;
#pragma unroll
  for (int k = 0; k < 8; ++k) acch[k] = (_Float16)0;
  float l;
  if (deg <= 64) {
    int s_l = (lane < deg) ? csr_src[beg + lane] : 0;
    float e = (lane < deg) ? leaky02(al_s[s_l] + ad) : -3.4e38f;
    float m = wave_max64(e);
    float ex = (lane < deg) ? expf(e - m) : 0.0f;
    l = wave_sum64(ex);
    int ng = (deg + 7) >> 3;  // <= 8, wave-uniform
    int ss[8]; _Float16 aa[8]; v8h vv[8];
#pragma unroll
    for (int u = 0; u < 8; ++u)
      if (u < ng) {
        int idx = u * 8 + grp;  // <= 63; pads: ex=0, s=0
        ss[u] = __shfl(s_l, idx, 64);
        aa[u] = (_Float16)__shfl(ex, idx, 64);
      }
#pragma unroll
    for (int u = 0; u < 8; ++u)
      if (u < ng) vv[u] = *(const v8h*)(hp + (size_t)ss[u] * 64 + fb);
#pragma unroll
    for (int u = 0; u < 8; ++u)
      if (u < ng) acch += bcast8(aa[u]) * vv[u];
  } else {
    float m = -3.4e38f;
    for (int base = beg; base < end; base += 64) {
      int nch = min(64, end - base);
      int s = (lane < nch) ? csr_src[base + lane] : 0;
      float e = (lane < nch) ? leaky02(al_s[s] + ad) : -3.4e38f;
      m = fmaxf(m, wave_max64(e));
    }
    l = 0.0f;
    for (int base = beg; base < end; base += 64) {
      int nch = min(64, end - base);
      int s_l = (lane < nch) ? csr_src[base + lane] : 0;
      float ex = (lane < nch) ? expf(leaky02(al_s[s_l] + ad) - m) : 0.0f;
      l += wave_sum64(ex);
      for (int j = 0; j < nch; j += 8) {
        int idx = j + grp;
        int s = __shfl(s_l, idx, 64);
        _Float16 a = (_Float16)__shfl(ex, idx, 64);
        v8h v = *(const v8h*)(hp + (size_t)s * 64 + fb);
        acch += bcast8(a) * v;
      }
    }
  }
  float acc[8];
#pragma unroll
  for (int k = 0; k < 8; ++k) acc[k] = (float)acch[k];
#pragma unroll
  for (int o = 8; o < 64; o <<= 1)
#pragma unroll
    for (int k = 0; k < 8; ++k) acc[k] += __shfl_xor(acc[k], o, 64);
  if (lane < 8) {
    v8h ov;
#pragma unroll
    for (int k = 0; k < 8; ++k)
      ov[k] = (_Float16)(acc[k] / l + b[fb + k]);  // no relu on layer 2
    *(v8h*)((_Float16*)out + (size_t)wid * 64 + fb) = ov;
  }
}

// ---------------------------------------------------------------- pool + head
__device__ __forceinline__ int lower_bound(const int* __restrict__ a, int n, int v) {
  int lo = 0, hi = n;
  while (lo < hi) {
    int mid = (lo + hi) >> 1;
    if (a[mid] < v) lo = mid + 1; else hi = mid;
  }
  return lo;
}

// stage A: wave per (graph, slice): sum a contiguous slice of the graph's rows.
__launch_bounds__(BDIM) __global__
void pool_partial(const __half* __restrict__ x3, const int* __restrict__ batch,
                  float* __restrict__ part, int N, int G) {
  int wid = blockIdx.x * (BDIM / 64) + (threadIdx.x >> 6);
  int lane = threadIdx.x & 63;
  if (wid >= G * PS) return;
  int g = wid / PS, s = wid % PS;
  int beg = lower_bound(batch, N, g);
  int end = lower_bound(batch, N, g + 1);
  int len = end - beg;
  int lo = beg + (int)((long long)len * s / PS);
  int hi = beg + (int)((long long)len * (s + 1) / PS);
  float acc = 0.0f;
  int n = lo;
  for (; n + 4 <= hi; n += 4) {  // 4 independent line-loads in flight
    float a0 = __half2float(x3[(size_t)(n + 0) * 64 + lane]);
    float a1 = __half2float(x3[(size_t)(n + 1) * 64 + lane]);
    float a2 = __half2float(x3[(size_t)(n + 2) * 64 + lane]);
    float a3 = __half2float(x3[(size_t)(n + 3) * 64 + lane]);
    acc += (a0 + a1) + (a2 + a3);
  }
  for (; n < hi; ++n) acc += __half2float(x3[(size_t)n * 64 + lane]);
  part[(size_t)wid * 64 + lane] = acc;
}

// stage B: wave per graph: reduce PS partials, mean, FC, log_softmax.
__launch_bounds__(BDIM) __global__
void pool_head(const float* __restrict__ part, const int* __restrict__ batch,
               const float* __restrict__ Wfc, const float* __restrict__ bfc,
               float* __restrict__ out, int N, int G) {
  int wid = blockIdx.x * (BDIM / 64) + (threadIdx.x >> 6);
  int lane = threadIdx.x & 63;
  if (wid >= G) return;
  float acc = 0.0f;
#pragma unroll
  for (int s = 0; s < PS; ++s) acc += part[((size_t)wid * PS + s) * 64 + lane];
  int beg = lower_bound(batch, N, wid);
  int end = lower_bound(batch, N, wid + 1);
  float p = (end > beg) ? acc / (float)(end - beg) : 0.0f;
  float l0 = wave_sum64(p * Wfc[lane * 2 + 0]);
  float l1 = wave_sum64(p * Wfc[lane * 2 + 1]);
  if (lane == 0) {
    l0 += bfc[0];
    l1 += bfc[1];
    float m = fmaxf(l0, l1);
    float ls = m + logf(expf(l0 - m) + expf(l1 - m));
    out[wid * 2 + 0] = l0 - ls;
    out[wid * 2 + 1] = l1 - ls;
  }
}

// ---------------------------------------------------------------- launch

static inline int cdiv(int a, int b) { return (a + b - 1) / b; }

extern "C" void kernel_launch(void* const* d_in, const int* in_sizes, int n_in,
                              void* d_out, int out_size, void* d_ws, size_t ws_size,
                              hipStream_t stream) {
  const float* x      = (const float*)d_in[0];
  const int*   ei     = (const int*)d_in[1];
  const int*   batch  = (const int*)d_in[2];
  const float* W1     = (const float*)d_in[3];
  const float* b1     = (const float*)d_in[4];
  const float* W2     = (const float*)d_in[5];
  const float* a_src2 = (const float*)d_in[6];
  const float* a_dst2 = (const float*)d_in[7];
  const float* b2     = (const float*)d_in[8];
  const float* W3     = (const float*)d_in[9];
  const float* a_src3 = (const float*)d_in[10];
  const float* a_dst3 = (const float*)d_in[11];
  const float* b3     = (const float*)d_in[12];
  const float* Wfc    = (const float*)d_in[13];
  const float* bfc    = (const float*)d_in[14];
  float* out = (float*)d_out;

  const int N = in_sizes[2];       // 50000
  const int E = in_sizes[1] / 2;   // 800000
  const int G = out_size / 2;      // 512
  const int TOT = E + N;           // edges incl. self-loops
  const int bw  = cdiv(N, NB);     // dst-range per bucket (98)
  const int nWG = cdiv(TOT, CH);   // chunks (104)
  const int M   = NB * nWG;        // count-matrix size

  // workspace layout, fp16 buffers first (16B-aligned offsets)
  char* wsb = (char*)d_ws;
  __half* h1    = (__half*)wsb;                       // N*64 fp16
  __half* h2    = h1 + (size_t)N * 64;                // N*128 fp16 (reused as h3)
  __half* out1h = h2 + (size_t)N * 128;               // N*64 fp16 (x1)
  __half* out2h = out1h + (size_t)N * 64;             // N*128 fp16 (x2)
  __half* out3h = out2h + (size_t)N * 128;            // N*64 fp16 (x3)
  float*  dis   = (float*)(out3h + (size_t)N * 64);   // N
  float*  al_s  = dis + N;                            // N*2 planar
  float*  al_d  = al_s + (size_t)N * 2;               // N*2 planar
  float*  part  = al_d + (size_t)N * 2;               // G*PS*64
  int* counts   = (int*)(part + (size_t)G * PS * 64); // M
  int* off      = counts + M;                         // M
  int* btot     = off + M;                            // NB
  int* bbase    = btot + NB;                          // NB+1
  unsigned int* ebuf = (unsigned int*)(bbase + NB + 1);  // TOT
  int* csr_src  = (int*)(ebuf + TOT);                 // TOT
  int* row_ptr  = csr_src + TOT;                      // N+1

  // ---- CSR build: atomic-free radix bucketing, factored parallel scan
  hist_a<<<nWG, BDIM, 0, stream>>>(ei, E, TOT, bw, counts, nWG);
  scan_bucket<<<cdiv(NB, 4), BDIM, 0, stream>>>(counts, nWG, off, btot);
  scan_tot<<<1, 512, 0, stream>>>(btot, bbase, row_ptr, N, TOT);
  bucket_b<<<nWG, BDIM, 0, stream>>>(ei, E, TOT, bw, off, bbase, nWG, ebuf);
  csr_c<<<NB, BDIM, 0, stream>>>(ebuf, bbase, N, bw, row_ptr, dis, csr_src);

  // ---- GCN layer (h1 pre-scaled by dis[row] in GEMM epilogue)
  gemm_mfma<128, 64, true, 0, true><<<cdiv(N, 64), BDIM, 0, stream>>>(
      x, W1, (_Float16*)h1, dis, nullptr, nullptr, nullptr, nullptr, N);
  gcn_gather<<<cdiv(N, 4), BDIM, 0, stream>>>(h1, row_ptr, csr_src, dis, b1, out1h, N);

  // ---- GAT layer 1 (heads=2, concat; att_coef fused into GEMM epilogue,
  //      softmax fused into accumulate)
  gemm_mfma<64, 128, false, 2, false><<<cdiv(N, 64), BDIM, 0, stream>>>(
      out1h, W2, (_Float16*)h2, nullptr, a_src2, a_dst2, al_s, al_d, N);
  gat_fused2<<<cdiv(N, 4), BDIM, 0, stream>>>(h2, row_ptr, csr_src, al_s, al_d,
                                              b2, out2h, N);

  // ---- GAT layer 2 (heads=1, mean == identity)
  __half* h3 = h2;  // h2 dead after gat_fused2
  gemm_mfma<128, 64, false, 1, false><<<cdiv(N, 64), BDIM, 0, stream>>>(
      out2h, W3, (_Float16*)h3, nullptr, a_src3, a_dst3, al_s, al_d, N);
  gat_fused1<<<cdiv(N, 4), BDIM, 0, stream>>>(h3, row_ptr, csr_src, al_s, al_d,
                                              b3, out3h, N);

  // ---- global mean pool + fc + log_softmax (atomic-free; batch is sorted)
  pool_partial<<<cdiv(G * PS, 4), BDIM, 0, stream>>>(out3h, batch, part, N, G);
  pool_head<<<cdiv(G, 4), BDIM, 0, stream>>>(part, batch, Wfc, bfc, out, N, G);
}